// Round 5
// baseline (6358.897 us; speedup 1.0000x reference)
//
#include <hip/hip_runtime.h>
#include <hip/hip_bf16.h>

#define T_SEQ 512
#define BATCH 64
#define IN0   128
#define HID   512
#define OUTF  256
#define G4    (4*HID)     // 2048 gate rows
#define NWG_L 64          // worker WGs per layer (each owns 8 hidden units)
#define FSTR  32          // flag stride in u32 -> one 128B line per producer

typedef __attribute__((ext_vector_type(8))) short short8;   // 8 bf16 (MFMA A/B frag)
typedef __attribute__((ext_vector_type(4))) float f32x4;    // MFMA C/D frag
typedef unsigned short u16;

__device__ __forceinline__ float sigmoidf_(float x) { return 1.f / (1.f + __expf(-x)); }
__device__ __forceinline__ float tanhf_(float x)    { return 1.f - 2.f / (1.f + __expf(2.f * x)); }

__device__ __forceinline__ u16 f2bf(float f) {
    union { float f; unsigned u; } a; a.f = f;
    unsigned u = a.u;
    return (u16)((u + 0x7fffu + ((u >> 16) & 1u)) >> 16);   // RNE
}

// sc0 load: bypass the CU's L1, served by the XCD's L2 (the local coherence
// point for same-XCD producer/consumer). NOT valid across XCDs.
__device__ __forceinline__ unsigned ld_flag_sc0(const unsigned* p) {
    unsigned v;
    asm volatile("global_load_dword %0, %1, off sc0\n\ts_waitcnt vmcnt(0)"
                 : "=v"(v) : "v"(p) : "memory");
    return v;
}

// Local-L2 poll: lane l watches flags[l*FSTR] via sc0. Safety net: every 16
// iters also read the agent-scope mirror (IC) and take the per-lane max, so
// progress never depends on sc0 semantics alone.
__device__ __forceinline__ void poll_local(const unsigned* lf, const unsigned* mf,
                                           int lane, unsigned tgt) {
    unsigned best = 0, it = 0;
    for (;;) {
        unsigned v = ld_flag_sc0(lf + (size_t)lane * FSTR);
        best = v > best ? v : best;
        if (__all((int)(best >= tgt))) return;
        if ((++it & 15u) == 0u) {
            unsigned m = __hip_atomic_load(mf + (size_t)lane * FSTR,
                                           __ATOMIC_RELAXED, __HIP_MEMORY_SCOPE_AGENT);
            best = m > best ? m : best;
            if (__all((int)(best >= tgt))) return;
        }
        __builtin_amdgcn_s_sleep(1);
    }
}

// Cross-XCD poll at the device coherence point (IC).
__device__ __forceinline__ void poll_agent(const unsigned* flags, int lane, unsigned tgt) {
    for (;;) {
        unsigned v = __hip_atomic_load(flags + (size_t)lane * FSTR,
                                       __ATOMIC_RELAXED, __HIP_MEMORY_SCOPE_AGENT);
        if (__all((int)(v >= tgt))) return;
        __builtin_amdgcn_s_sleep(2);
    }
}

// ---------------- f32 -> bf16 conversion ----------------
__global__ void cvt_f32_bf16(const float* __restrict__ in, u16* __restrict__ out, int n4) {
    int i = blockIdx.x * blockDim.x + threadIdx.x;
    if (i < n4) {
        float4 v = reinterpret_cast<const float4*>(in)[i];
        ushort4 o;
        o.x = f2bf(v.x); o.y = f2bf(v.y); o.z = f2bf(v.z); o.w = f2bf(v.w);
        reinterpret_cast<ushort4*>(out)[i] = o;
    }
}

// ---------------- XCD-localized pipelined 2-layer LSTM ----------------
// Layer 0 lives entirely on one XCD, layer 1 on another (self-claimed via
// XCC_ID + tickets). Intra-layer sync: plain stores + sc0 polls in the local
// L2. Cross-layer pipe y0: agent write-through stores with a one-step
// deferred announce (flags0r), so IC ack latency is off the recurrence path.
template<int LAYER>
__device__ __forceinline__ void run_layer(
    const u16* __restrict__ asrc,   // L0: x_bf [T,B,128]; L1: y0 [T,B,512]
    const u16* __restrict__ wih, const u16* __restrict__ whh,
    const float* __restrict__ bias,
    u16* __restrict__ ybuf,         // own-layer h/y storage [T,B,512]
    float* __restrict__ hNout, float* __restrict__ cNout,
    unsigned* fl_own,               // local flags (plain-store / sc0-load domain)
    unsigned* fm_own,               // agent mirror of local flags (safety net)
    unsigned* f_cross,              // L0: announce target; L1: poll source (IC)
    int g,
    u16 (*lds_w)[32][512], float (*lds_g)[33], float (*lds_b)[16])
{
    constexpr int KIN = (LAYER == 0) ? IN0 : HID;
    constexpr int KS1 = KIN / 32;        // input-part K slices
    constexpr int KS  = KS1 + 16;        // + recurrent K slices

    const int tid  = threadIdx.x;
    const int lane = tid & 63;
    const int w    = tid >> 6;           // wave id -> batch rows 16w..16w+15
    const int ubase = 8 * g;

    // ---- pack weights into LDS in MFMA B-frag order (2 col-tiles) ----
    for (int idx = tid; idx < 2 * KS * 64; idx += 256) {
        int nt  = (idx >= KS * 64) ? 1 : 0;
        int rem = idx - nt * KS * 64;
        int ks = rem >> 6, s = rem & 63, q = s & 15, kq = s >> 4;
        int r = (q >> 2) * HID + ubase + 4 * nt + (q & 3);
        const u16* src = (ks < KS1)
            ? wih + (size_t)r * KIN + (size_t)ks * 32 + kq * 8
            : whh + (size_t)r * HID + (size_t)(ks - KS1) * 32 + kq * 8;
        *reinterpret_cast<uint4*>(&lds_w[nt][ks][s * 8]) =
            *reinterpret_cast<const uint4*>(src);
    }
    if (tid < 32) {
        int nt = tid >> 4, q = tid & 15;
        lds_b[nt][q] = bias[(q >> 2) * HID + ubase + 4 * nt + (q & 3)];
    }
    __syncthreads();

    const int pb  = tid & 63;   // pointwise: batch index
    const int pu2 = tid >> 6;   // pointwise: unit-pair index (0..3)
    float c0 = 0.f, c1 = 0.f;

    const int arow = 16 * w + (lane & 15);
    const int koff = (lane >> 4) * 8;

    for (int t = 0; t < T_SEQ; ++t) {
        f32x4 ac0[4] = {{0,0,0,0},{0,0,0,0},{0,0,0,0},{0,0,0,0}};
        f32x4 ac1[4] = {{0,0,0,0},{0,0,0,0},{0,0,0,0},{0,0,0,0}};

        if (LAYER == 0) {
            // x[t] contribution — no dependency, runs before any wait
            const u16* ap = asrc + ((size_t)t * BATCH + arow) * KIN + koff;
            short8 a[KS1];
            #pragma unroll
            for (int j = 0; j < KS1; ++j)
                a[j] = *reinterpret_cast<const short8*>(ap + j * 32);
            #pragma unroll
            for (int j = 0; j < KS1; ++j) {
                ac0[j & 3] = __builtin_amdgcn_mfma_f32_16x16x32_bf16(
                    a[j], *reinterpret_cast<const short8*>(&lds_w[0][j][lane * 8]), ac0[j & 3], 0, 0, 0);
                ac1[j & 3] = __builtin_amdgcn_mfma_f32_16x16x32_bf16(
                    a[j], *reinterpret_cast<const short8*>(&lds_w[1][j][lane * 8]), ac1[j & 3], 0, 0, 0);
            }
        }

        // ---- waits: parallel polls on separate waves, one barrier join ----
        if (LAYER == 0) {
            if (t > 0) {
                if (w == 0) poll_local(fl_own, fm_own, lane, (unsigned)t);
                __syncthreads();
            }
        } else {
            if (w == 0 && t > 0) poll_local(fl_own, fm_own, lane, (unsigned)t);
            if (w == 1) poll_agent(f_cross, lane, (unsigned)(t + 1));   // y0[t] in IC
            __syncthreads();
        }

        // own-layer recurrent h[t-1] contribution (local L2 reads)
        if (t > 0) {
            const u16* hp = ybuf + ((size_t)(t - 1) * BATCH + arow) * HID + koff;
            short8 a[16];
            #pragma unroll
            for (int j = 0; j < 16; ++j)
                a[j] = *reinterpret_cast<const short8*>(hp + j * 32);
            #pragma unroll
            for (int j = 0; j < 16; ++j) {
                ac0[j & 3] = __builtin_amdgcn_mfma_f32_16x16x32_bf16(
                    a[j], *reinterpret_cast<const short8*>(&lds_w[0][KS1 + j][lane * 8]), ac0[j & 3], 0, 0, 0);
                ac1[j & 3] = __builtin_amdgcn_mfma_f32_16x16x32_bf16(
                    a[j], *reinterpret_cast<const short8*>(&lds_w[1][KS1 + j][lane * 8]), ac1[j & 3], 0, 0, 0);
            }
        }

        // L1: y0[t] contribution (IC-sourced, fills local L2 once per step)
        if (LAYER == 1) {
            const u16* ap = asrc + ((size_t)t * BATCH + arow) * HID + koff;
            short8 a[16];
            #pragma unroll
            for (int j = 0; j < 16; ++j)
                a[j] = *reinterpret_cast<const short8*>(ap + j * 32);
            #pragma unroll
            for (int j = 0; j < 16; ++j) {
                ac0[j & 3] = __builtin_amdgcn_mfma_f32_16x16x32_bf16(
                    a[j], *reinterpret_cast<const short8*>(&lds_w[0][j][lane * 8]), ac0[j & 3], 0, 0, 0);
                ac1[j & 3] = __builtin_amdgcn_mfma_f32_16x16x32_bf16(
                    a[j], *reinterpret_cast<const short8*>(&lds_w[1][j][lane * 8]), ac1[j & 3], 0, 0, 0);
            }
        }

        f32x4 s0 = (ac0[0] + ac0[1]) + (ac0[2] + ac0[3]);
        f32x4 s1 = (ac1[0] + ac1[1]) + (ac1[2] + ac1[3]);
        // D frag: row = 16w + (lane>>4)*4 + j (batch), col = lane&15 (q)
        #pragma unroll
        for (int j = 0; j < 4; ++j) {
            int row = 16 * w + (lane >> 4) * 4 + j;
            lds_g[row][lane & 15]        = s0[j];
            lds_g[row][16 + (lane & 15)] = s1[j];
        }
        __syncthreads();

        // pointwise cell update (f32): thread (pb,pu2) owns units 2pu2, 2pu2+1
        unsigned pack;
        unsigned* yp32;
        {
            const int nt = pu2 >> 1;
            const int dq = (2 * pu2) & 3;
            const float* gr = &lds_g[pb][nt * 16];
            const float* br = lds_b[nt];
            float gi0 = sigmoidf_(gr[dq]      + br[dq]);
            float gf0 = sigmoidf_(gr[4 + dq]  + br[4 + dq]);
            float gg0 = tanhf_(   gr[8 + dq]  + br[8 + dq]);
            float go0 = sigmoidf_(gr[12 + dq] + br[12 + dq]);
            c0 = gf0 * c0 + gi0 * gg0;
            float h0v = go0 * tanhf_(c0);
            float gi1 = sigmoidf_(gr[dq + 1]      + br[dq + 1]);
            float gf1 = sigmoidf_(gr[4 + dq + 1]  + br[4 + dq + 1]);
            float gg1 = tanhf_(   gr[8 + dq + 1]  + br[8 + dq + 1]);
            float go1 = sigmoidf_(gr[12 + dq + 1] + br[12 + dq + 1]);
            c1 = gf1 * c1 + gi1 * gg1;
            float h1v = go1 * tanhf_(c1);

            pack = (unsigned)f2bf(h0v) | ((unsigned)f2bf(h1v) << 16);
            yp32 = reinterpret_cast<unsigned*>(ybuf)
                 + ((size_t)t * BATCH + pb) * (HID / 2) + (ubase + 2 * pu2) / 2;
            *yp32 = pack;                       // plain store -> local L2 (fast)

            if (t == T_SEQ - 1) {
                hNout[pb * HID + ubase + 2 * pu2]     = h0v;
                hNout[pb * HID + ubase + 2 * pu2 + 1] = h1v;
                cNout[pb * HID + ubase + 2 * pu2]     = c0;
                cNout[pb * HID + ubase + 2 * pu2 + 1] = c1;
            }
        }

        // local publish: L2 ack only (cheap), then plain flag + agent mirror.
        asm volatile("s_waitcnt vmcnt(0)" ::: "memory");
        __syncthreads();
        if (tid == 0) {
            *(volatile unsigned*)(fl_own + (size_t)g * FSTR) = (unsigned)(t + 1);
            __hip_atomic_store(fm_own + (size_t)g * FSTR, (unsigned)(t + 1),
                               __ATOMIC_RELAXED, __HIP_MEMORY_SCOPE_AGENT);
            if (LAYER == 0)   // deferred announce: y0_ic[0..t-1] acked by THIS step's vmcnt
                __hip_atomic_store(f_cross + (size_t)g * FSTR, (unsigned)t,
                                   __ATOMIC_RELAXED, __HIP_MEMORY_SCOPE_AGENT);
        }
        if (LAYER == 0)       // push y0[t] to IC; acked by NEXT step's vmcnt(0)
            __hip_atomic_store(yp32, pack, __ATOMIC_RELAXED, __HIP_MEMORY_SCOPE_AGENT);
    }

    if (LAYER == 0) {         // final announce: all 512 steps in IC
        asm volatile("s_waitcnt vmcnt(0)" ::: "memory");
        if (tid == 0)
            __hip_atomic_store(f_cross + (size_t)g * FSTR, (unsigned)T_SEQ,
                               __ATOMIC_RELAXED, __HIP_MEMORY_SCOPE_AGENT);
    }
}

__global__ __launch_bounds__(256, 1)
void lstm_fused(const u16* __restrict__ x_bf,
                const u16* __restrict__ wih0, const u16* __restrict__ whh0, const float* __restrict__ b0,
                const u16* __restrict__ wih1, const u16* __restrict__ whh1, const float* __restrict__ b1,
                u16* __restrict__ y0, u16* __restrict__ y1,
                float* __restrict__ hN, float* __restrict__ cN,
                unsigned* __restrict__ ctl)
{
    __shared__ __align__(16) u16 lds_w[2][32][512];   // 64 KB
    __shared__ float lds_g[BATCH][33];
    __shared__ float lds_b[2][16];
    __shared__ int s_layer, s_role;

    // ---- self-placement: first two XCDs to pioneer host the two layers ----
    if (threadIdx.x == 0) {
        unsigned xcc;
        asm volatile("s_getreg_b32 %0, hwreg(HW_REG_XCC_ID)" : "=s"(xcc));
        xcc &= 7u;
        unsigned* pioneer = ctl + 0;    // [8]
        unsigned* lxcd    = ctl + 8;    // [8]: 0=unset 1=L0 2=L1 3=idle
        unsigned* ltick   = ctl + 16;
        unsigned* rtick   = ctl + 24;   // [2]
        if (__hip_atomic_fetch_add(&pioneer[xcc], 1u,
                                   __ATOMIC_RELAXED, __HIP_MEMORY_SCOPE_AGENT) == 0u) {
            unsigned li = __hip_atomic_fetch_add(ltick, 1u,
                                                 __ATOMIC_RELAXED, __HIP_MEMORY_SCOPE_AGENT);
            __hip_atomic_store(&lxcd[xcc], (li < 2u) ? (li + 1u) : 3u,
                               __ATOMIC_RELAXED, __HIP_MEMORY_SCOPE_AGENT);
        }
        unsigned lx;
        do {
            lx = __hip_atomic_load(&lxcd[xcc], __ATOMIC_RELAXED, __HIP_MEMORY_SCOPE_AGENT);
            if (lx == 0u) __builtin_amdgcn_s_sleep(1);
        } while (lx == 0u);
        int layer = (lx <= 2u) ? (int)lx - 1 : -1;
        int role = -1;
        if (layer >= 0) {
            unsigned r = __hip_atomic_fetch_add(&rtick[layer], 1u,
                                                __ATOMIC_RELAXED, __HIP_MEMORY_SCOPE_AGENT);
            if (r < NWG_L) role = (int)r;
        }
        s_layer = layer; s_role = role;
    }
    __syncthreads();
    const int layer = s_layer, role = s_role;
    if (role < 0) return;     // non-worker: free the slot

    unsigned* flags0  = ctl + 64;
    unsigned* flags1  = flags0  + NWG_L * FSTR;
    unsigned* flags0m = flags1  + NWG_L * FSTR;
    unsigned* flags1m = flags0m + NWG_L * FSTR;
    unsigned* flags0r = flags1m + NWG_L * FSTR;

    if (layer == 0) {
        run_layer<0>(x_bf, wih0, whh0, b0, y0, hN, cN,
                     flags0, flags0m, flags0r, role, lds_w, lds_g, lds_b);
    } else {
        run_layer<1>(y0, wih1, whh1, b1, y1, hN + BATCH * HID, cN + BATCH * HID,
                     flags1, flags1m, flags0r, role, lds_w, lds_g, lds_b);
    }
}

// ---------------- final FC: out[32768,256] = y1[32768,512] @ fc_w[256,512]^T + b ----------
__global__ __launch_bounds__(256)
void fc_kernel(const u16* __restrict__ y1, const u16* __restrict__ fcw,
               const float* __restrict__ fcb, float* __restrict__ out)
{
    const int tid  = threadIdx.x;
    const int lane = tid & 63;
    const int wgid = blockIdx.x * 4 + (tid >> 6);
    const int nq   = wgid & 3;
    const int mt0  = wgid >> 2;

    for (int j = 0; j < 8; ++j) {
        int mt = mt0 + j * 256;
        f32x4 acc[4] = {{0,0,0,0},{0,0,0,0},{0,0,0,0},{0,0,0,0}};
        const u16* arow = y1 + ((size_t)mt * 16 + (lane & 15)) * HID + (lane >> 4) * 8;
        #pragma unroll
        for (int ks = 0; ks < 16; ++ks) {
            short8 a = *reinterpret_cast<const short8*>(arow + ks * 32);
            #pragma unroll
            for (int nt = 0; nt < 4; ++nt) {
                const u16* brow = fcw + ((size_t)(nq * 64 + nt * 16 + (lane & 15))) * HID
                                      + ks * 32 + (lane >> 4) * 8;
                short8 b = *reinterpret_cast<const short8*>(brow);
                acc[nt] = __builtin_amdgcn_mfma_f32_16x16x32_bf16(a, b, acc[nt], 0, 0, 0);
            }
        }
        #pragma unroll
        for (int nt = 0; nt < 4; ++nt) {
            int col = nq * 64 + nt * 16 + (lane & 15);
            float bb = fcb[col];
            #pragma unroll
            for (int jj = 0; jj < 4; ++jj) {
                int row = mt * 16 + (lane >> 4) * 4 + jj;
                out[(size_t)row * OUTF + col] = acc[nt][jj] + bb;
            }
        }
    }
}

extern "C" void kernel_launch(void* const* d_in, const int* in_sizes, int n_in,
                              void* d_out, int out_size, void* d_ws, size_t ws_size,
                              hipStream_t stream)
{
    const float* x    = (const float*)d_in[0];
    const float* wih0 = (const float*)d_in[1];
    const float* whh0 = (const float*)d_in[2];
    const float* b0   = (const float*)d_in[3];
    const float* wih1 = (const float*)d_in[4];
    const float* whh1 = (const float*)d_in[5];
    const float* b1   = (const float*)d_in[6];
    const float* fcw  = (const float*)d_in[7];
    const float* fcb  = (const float*)d_in[8];
    float* out = (float*)d_out;

    // ctl: pioneer[8], lxcd[8], ltick, rtick[2], pads, then 5 flag arrays
    const size_t ctl_u32 = 64 + (size_t)5 * NWG_L * FSTR;     // 10304 u32
    const size_t ctl_bytes = ctl_u32 * 4;                     // 41216 B

    char* ws = (char*)d_ws;
    size_t off = 0;
    unsigned* ctl = (unsigned*)ws;                    off += (ctl_bytes + 255) & ~(size_t)255;
    u16* x_bf    = (u16*)(ws + off);                  off += (size_t)T_SEQ * BATCH * IN0 * 2;
    u16* wih0_bf = (u16*)(ws + off);                  off += (size_t)G4 * IN0 * 2;
    u16* whh0_bf = (u16*)(ws + off);                  off += (size_t)G4 * HID * 2;
    u16* wih1_bf = (u16*)(ws + off);                  off += (size_t)G4 * HID * 2;
    u16* whh1_bf = (u16*)(ws + off);                  off += (size_t)G4 * HID * 2;
    u16* fcw_bf  = (u16*)(ws + off);                  off += (size_t)OUTF * HID * 2;
    u16* y0      = (u16*)(ws + off);                  off += (size_t)T_SEQ * BATCH * HID * 2;
    u16* y1      = (u16*)(ws + off);                  off += (size_t)T_SEQ * BATCH * HID * 2;

    hipMemsetAsync(ctl, 0, ctl_bytes, stream);

    auto conv = [&](const float* in, u16* o, int n) {
        int n4 = n / 4;
        cvt_f32_bf16<<<(n4 + 255) / 256, 256, 0, stream>>>(in, o, n4);
    };
    conv(x,    x_bf,    T_SEQ * BATCH * IN0);
    conv(wih0, wih0_bf, G4 * IN0);
    conv(whh0, whh0_bf, G4 * HID);
    conv(wih1, wih1_bf, G4 * HID);
    conv(whh1, whh1_bf, G4 * HID);
    conv(fcw,  fcw_bf,  OUTF * HID);

    float* outFC = out;
    float* hN = out + (size_t)T_SEQ * BATCH * OUTF;     // [2,B,H]
    float* cN = hN + 2 * BATCH * HID;                   // [2,B,H]

    lstm_fused<<<1024, 256, 0, stream>>>(x_bf, wih0_bf, whh0_bf, b0,
                                         wih1_bf, whh1_bf, b1,
                                         y0, y1, hN, cN, ctl);
    fc_kernel<<<256, 256, 0, stream>>>(y1, fcw_bf, fcb, outFC);
}

// Round 6
// 3497.826 us; speedup vs baseline: 1.8180x; 1.8180x over previous
//
#include <hip/hip_runtime.h>
#include <hip/hip_bf16.h>

#define T_SEQ 512
#define BATCH 64
#define IN0   128
#define HID   512
#define OUTF  256
#define G4    (4*HID)     // 2048 gate rows
#define NWG_L 64          // workgroups per layer (each owns 8 hidden units)
#define FSTR  32          // flag stride in u32 -> one 128B line per producer

typedef __attribute__((ext_vector_type(8))) short short8;   // 8 bf16 (MFMA A/B frag)
typedef __attribute__((ext_vector_type(4))) float f32x4;    // MFMA C/D frag
typedef unsigned short u16;
typedef unsigned long long u64;

__device__ __forceinline__ float sigmoidf_(float x) { return 1.f / (1.f + __expf(-x)); }
__device__ __forceinline__ float tanhf_(float x)    { return 1.f - 2.f / (1.f + __expf(2.f * x)); }

__device__ __forceinline__ u16 f2bf(float f) {
    union { float f; unsigned u; } a; a.f = f;
    unsigned u = a.u;
    return (u16)((u + 0x7fffu + ((u >> 16) & 1u)) >> 16);   // RNE
}

// Poll: lane l watches flags[l*FSTR] (one 128B line per producer). Relaxed
// agent loads read the coherence point without cache maintenance; rare
// acquire as a progress safety net.
__device__ __forceinline__ void wave_poll_ge(const unsigned* flags, int lane, unsigned tgt) {
    unsigned it = 0;
    for (;;) {
        unsigned v = __hip_atomic_load(flags + (size_t)lane * FSTR,
                                       __ATOMIC_RELAXED, __HIP_MEMORY_SCOPE_AGENT);
        if (__all((int)(v >= tgt))) return;
        __builtin_amdgcn_s_sleep(1);
        if ((++it & 2047u) == 0u)
            (void)__hip_atomic_load(flags, __ATOMIC_ACQUIRE, __HIP_MEMORY_SCOPE_AGENT);
    }
}

// ---------------- f32 -> bf16 conversion ----------------
__global__ void cvt_f32_bf16(const float* __restrict__ in, u16* __restrict__ out, int n4) {
    int i = blockIdx.x * blockDim.x + threadIdx.x;
    if (i < n4) {
        float4 v = reinterpret_cast<const float4*>(in)[i];
        ushort4 o;
        o.x = f2bf(v.x); o.y = f2bf(v.y); o.z = f2bf(v.z); o.w = f2bf(v.w);
        reinterpret_cast<ushort4*>(out)[i] = o;
    }
}

// ---------------- fused pipelined 2-layer LSTM ----------------
// WG g in [0,64): layer 0, owns hidden units [8g, 8g+8) -> 32 gate rows as 2
// MFMA col-tiles. WG 64+g: layer 1, same ownership.
// flags[g*FSTR] = #steps completed by WG g of that layer.
// Publish path (slim): cell -> lds_h -> barrier -> WAVE 0 ONLY: 2x u64 agent
// stores (16B/lane, WG's full 1KB block) -> vmcnt(0) (wave-0 private) ->
// lane0 flag store. No trailing barrier: waves 1-3 run ahead.
template<int LAYER>
__device__ __forceinline__ void run_layer(
    const u16* __restrict__ asrc,   // L0: x_bf [T,B,128]; L1: y0 [T,B,512]
    const u16* __restrict__ wih, const u16* __restrict__ whh,
    const float* __restrict__ bias,
    u16* __restrict__ ybuf,         // own-layer h/y storage [T,B,512]
    float* __restrict__ hNout, float* __restrict__ cNout,
    unsigned* flags_own, unsigned* flags_dep, int g,
    u16 (*lds_w)[32][512], float (*lds_g)[33], float (*lds_b)[16],
    unsigned (*lds_h)[4])
{
    constexpr int KIN = (LAYER == 0) ? IN0 : HID;
    constexpr int KS1 = KIN / 32;        // input-part K slices
    constexpr int KS  = KS1 + 16;        // + recurrent K slices

    const int tid  = threadIdx.x;
    const int lane = tid & 63;
    const int w    = tid >> 6;           // wave id -> batch rows 16w..16w+15
    const int ubase = 8 * g;

    // ---- pack weights into LDS in MFMA B-frag order (2 col-tiles) ----
    for (int idx = tid; idx < 2 * KS * 64; idx += 256) {
        int nt  = (idx >= KS * 64) ? 1 : 0;
        int rem = idx - nt * KS * 64;
        int ks = rem >> 6, s = rem & 63, q = s & 15, kq = s >> 4;
        int r = (q >> 2) * HID + ubase + 4 * nt + (q & 3);   // global gate row
        const u16* src = (ks < KS1)
            ? wih + (size_t)r * KIN + (size_t)ks * 32 + kq * 8
            : whh + (size_t)r * HID + (size_t)(ks - KS1) * 32 + kq * 8;
        *reinterpret_cast<uint4*>(&lds_w[nt][ks][s * 8]) =
            *reinterpret_cast<const uint4*>(src);
    }
    if (tid < 32) {
        int nt = tid >> 4, q = tid & 15;
        lds_b[nt][q] = bias[(q >> 2) * HID + ubase + 4 * nt + (q & 3)];
    }
    __syncthreads();

    const int pb  = tid & 63;   // pointwise: batch index
    const int pu2 = tid >> 6;   // pointwise: unit-pair index (0..3)
    float c0 = 0.f, c1 = 0.f;

    const int arow = 16 * w + (lane & 15);
    const int koff = (lane >> 4) * 8;

    for (int t = 0; t < T_SEQ; ++t) {
        f32x4 ac0[4] = {{0,0,0,0},{0,0,0,0},{0,0,0,0},{0,0,0,0}};
        f32x4 ac1[4] = {{0,0,0,0},{0,0,0,0},{0,0,0,0},{0,0,0,0}};

        if (LAYER == 0) {
            // x[t] contribution — no dependency, runs before any wait
            const u16* ap = asrc + ((size_t)t * BATCH + arow) * KIN + koff;
            short8 a[KS1];
            #pragma unroll
            for (int j = 0; j < KS1; ++j)
                a[j] = *reinterpret_cast<const short8*>(ap + j * 32);
            #pragma unroll
            for (int j = 0; j < KS1; ++j) {
                ac0[j & 3] = __builtin_amdgcn_mfma_f32_16x16x32_bf16(
                    a[j], *reinterpret_cast<const short8*>(&lds_w[0][j][lane * 8]), ac0[j & 3], 0, 0, 0);
                ac1[j & 3] = __builtin_amdgcn_mfma_f32_16x16x32_bf16(
                    a[j], *reinterpret_cast<const short8*>(&lds_w[1][j][lane * 8]), ac1[j & 3], 0, 0, 0);
            }
        }

        // ---- waits: parallel polls on separate waves, one barrier join ----
        if (LAYER == 0) {
            if (t > 0) {
                if (w == 0) wave_poll_ge(flags_own, lane, (unsigned)t);
                __syncthreads();
            }
        } else {
            if (w == 0 && t > 0) wave_poll_ge(flags_own, lane, (unsigned)t);   // h1[t-1]
            if (w == 1) wave_poll_ge(flags_dep, lane, (unsigned)(t + 1));      // y0[t]
            __syncthreads();
        }

        // own-layer recurrent h[t-1] contribution
        if (t > 0) {
            const u16* hp = ybuf + ((size_t)(t - 1) * BATCH + arow) * HID + koff;
            short8 a[16];
            #pragma unroll
            for (int j = 0; j < 16; ++j)
                a[j] = *reinterpret_cast<const short8*>(hp + j * 32);
            #pragma unroll
            for (int j = 0; j < 16; ++j) {
                ac0[j & 3] = __builtin_amdgcn_mfma_f32_16x16x32_bf16(
                    a[j], *reinterpret_cast<const short8*>(&lds_w[0][KS1 + j][lane * 8]), ac0[j & 3], 0, 0, 0);
                ac1[j & 3] = __builtin_amdgcn_mfma_f32_16x16x32_bf16(
                    a[j], *reinterpret_cast<const short8*>(&lds_w[1][KS1 + j][lane * 8]), ac1[j & 3], 0, 0, 0);
            }
        }

        // L1: y0[t] contribution
        if (LAYER == 1) {
            const u16* ap = asrc + ((size_t)t * BATCH + arow) * HID + koff;
            short8 a[16];
            #pragma unroll
            for (int j = 0; j < 16; ++j)
                a[j] = *reinterpret_cast<const short8*>(ap + j * 32);
            #pragma unroll
            for (int j = 0; j < 16; ++j) {
                ac0[j & 3] = __builtin_amdgcn_mfma_f32_16x16x32_bf16(
                    a[j], *reinterpret_cast<const short8*>(&lds_w[0][j][lane * 8]), ac0[j & 3], 0, 0, 0);
                ac1[j & 3] = __builtin_amdgcn_mfma_f32_16x16x32_bf16(
                    a[j], *reinterpret_cast<const short8*>(&lds_w[1][j][lane * 8]), ac1[j & 3], 0, 0, 0);
            }
        }

        f32x4 s0 = (ac0[0] + ac0[1]) + (ac0[2] + ac0[3]);
        f32x4 s1 = (ac1[0] + ac1[1]) + (ac1[2] + ac1[3]);
        // D frag: row = 16w + (lane>>4)*4 + j (batch), col = lane&15 (q)
        #pragma unroll
        for (int j = 0; j < 4; ++j) {
            int row = 16 * w + (lane >> 4) * 4 + j;
            lds_g[row][lane & 15]        = s0[j];
            lds_g[row][16 + (lane & 15)] = s1[j];
        }
        __syncthreads();

        // pointwise cell update (f32): thread (pb,pu2) owns units 2pu2, 2pu2+1
        {
            const int nt = pu2 >> 1;
            const int dq = (2 * pu2) & 3;
            const float* gr = &lds_g[pb][nt * 16];
            const float* br = lds_b[nt];
            float gi0 = sigmoidf_(gr[dq]      + br[dq]);
            float gf0 = sigmoidf_(gr[4 + dq]  + br[4 + dq]);
            float gg0 = tanhf_(   gr[8 + dq]  + br[8 + dq]);
            float go0 = sigmoidf_(gr[12 + dq] + br[12 + dq]);
            c0 = gf0 * c0 + gi0 * gg0;
            float h0v = go0 * tanhf_(c0);
            float gi1 = sigmoidf_(gr[dq + 1]      + br[dq + 1]);
            float gf1 = sigmoidf_(gr[4 + dq + 1]  + br[4 + dq + 1]);
            float gg1 = tanhf_(   gr[8 + dq + 1]  + br[8 + dq + 1]);
            float go1 = sigmoidf_(gr[12 + dq + 1] + br[12 + dq + 1]);
            c1 = gf1 * c1 + gi1 * gg1;
            float h1v = go1 * tanhf_(c1);

            lds_h[pb][pu2] = (unsigned)f2bf(h0v) | ((unsigned)f2bf(h1v) << 16);

            if (t == T_SEQ - 1) {
                hNout[pb * HID + ubase + 2 * pu2]     = h0v;
                hNout[pb * HID + ubase + 2 * pu2 + 1] = h1v;
                cNout[pb * HID + ubase + 2 * pu2]     = c0;
                cNout[pb * HID + ubase + 2 * pu2 + 1] = c1;
            }
        }
        __syncthreads();

        // slim publish: wave 0 stores the WG's whole 1KB block (16B/lane as
        // 2x u64 agent stores), waits only its own acks, then lane 0 raises
        // the flag. Waves 1-3 are already in step t+1.
        if (w == 0) {
            uint4 hv = *reinterpret_cast<const uint4*>(&lds_h[lane][0]);
            u64 q0 = (u64)hv.x | ((u64)hv.y << 32);
            u64 q1 = (u64)hv.z | ((u64)hv.w << 32);
            u64* yp = reinterpret_cast<u64*>(
                ybuf + ((size_t)t * BATCH + lane) * HID + ubase);
            __hip_atomic_store(yp + 0, q0, __ATOMIC_RELAXED, __HIP_MEMORY_SCOPE_AGENT);
            __hip_atomic_store(yp + 1, q1, __ATOMIC_RELAXED, __HIP_MEMORY_SCOPE_AGENT);
            asm volatile("s_waitcnt vmcnt(0)" ::: "memory");
            if (lane == 0)
                __hip_atomic_store(flags_own + (size_t)g * FSTR, (unsigned)(t + 1),
                                   __ATOMIC_RELAXED, __HIP_MEMORY_SCOPE_AGENT);
        }
    }
}

__global__ __launch_bounds__(256, 1)
void lstm_fused(const u16* __restrict__ x_bf,
                const u16* __restrict__ wih0, const u16* __restrict__ whh0, const float* __restrict__ b0,
                const u16* __restrict__ wih1, const u16* __restrict__ whh1, const float* __restrict__ b1,
                u16* __restrict__ y0, u16* __restrict__ y1,
                float* __restrict__ hN, float* __restrict__ cN,
                unsigned* __restrict__ ctr)
{
    __shared__ __align__(16) u16 lds_w[2][32][512];   // 64 KB (L0 uses KS=20 of 32)
    __shared__ float lds_g[BATCH][33];
    __shared__ float lds_b[2][16];
    __shared__ __align__(16) unsigned lds_h[BATCH][4];

    unsigned* flags0 = ctr;
    unsigned* flags1 = ctr + NWG_L * FSTR;

    const int wgid = blockIdx.x;
    if (wgid < NWG_L) {
        run_layer<0>(x_bf, wih0, whh0, b0, y0, hN, cN,
                     flags0, flags0, wgid, lds_w, lds_g, lds_b, lds_h);
    } else {
        run_layer<1>(y0, wih1, whh1, b1, y1, hN + BATCH * HID, cN + BATCH * HID,
                     flags1, flags0, wgid - NWG_L, lds_w, lds_g, lds_b, lds_h);
    }
}

// ---------------- final FC: out[32768,256] = y1[32768,512] @ fc_w[256,512]^T + b ----------
__global__ __launch_bounds__(256)
void fc_kernel(const u16* __restrict__ y1, const u16* __restrict__ fcw,
               const float* __restrict__ fcb, float* __restrict__ out)
{
    const int tid  = threadIdx.x;
    const int lane = tid & 63;
    const int wgid = blockIdx.x * 4 + (tid >> 6);  // 0..1023 waves
    const int nq   = wgid & 3;                     // 64-col block
    const int mt0  = wgid >> 2;                    // 0..255

    for (int j = 0; j < 8; ++j) {
        int mt = mt0 + j * 256;                    // M-tile 0..2047
        f32x4 acc[4] = {{0,0,0,0},{0,0,0,0},{0,0,0,0},{0,0,0,0}};
        const u16* arow = y1 + ((size_t)mt * 16 + (lane & 15)) * HID + (lane >> 4) * 8;
        #pragma unroll
        for (int ks = 0; ks < 16; ++ks) {
            short8 a = *reinterpret_cast<const short8*>(arow + ks * 32);
            #pragma unroll
            for (int nt = 0; nt < 4; ++nt) {
                const u16* brow = fcw + ((size_t)(nq * 64 + nt * 16 + (lane & 15))) * HID
                                      + ks * 32 + (lane >> 4) * 8;
                short8 b = *reinterpret_cast<const short8*>(brow);
                acc[nt] = __builtin_amdgcn_mfma_f32_16x16x32_bf16(a, b, acc[nt], 0, 0, 0);
            }
        }
        #pragma unroll
        for (int nt = 0; nt < 4; ++nt) {
            int col = nq * 64 + nt * 16 + (lane & 15);
            float bb = fcb[col];
            #pragma unroll
            for (int jj = 0; jj < 4; ++jj) {
                int row = mt * 16 + (lane >> 4) * 4 + jj;
                out[(size_t)row * OUTF + col] = acc[nt][jj] + bb;
            }
        }
    }
}

extern "C" void kernel_launch(void* const* d_in, const int* in_sizes, int n_in,
                              void* d_out, int out_size, void* d_ws, size_t ws_size,
                              hipStream_t stream)
{
    const float* x    = (const float*)d_in[0];
    const float* wih0 = (const float*)d_in[1];
    const float* whh0 = (const float*)d_in[2];
    const float* b0   = (const float*)d_in[3];
    const float* wih1 = (const float*)d_in[4];
    const float* whh1 = (const float*)d_in[5];
    const float* b1   = (const float*)d_in[6];
    const float* fcw  = (const float*)d_in[7];
    const float* fcb  = (const float*)d_in[8];
    float* out = (float*)d_out;

    const size_t flag_bytes = (size_t)2 * NWG_L * FSTR * 4;   // 16 KB

    char* ws = (char*)d_ws;
    size_t off = 0;
    unsigned* ctr = (unsigned*)ws;                    off += flag_bytes;
    u16* x_bf    = (u16*)(ws + off);                  off += (size_t)T_SEQ * BATCH * IN0 * 2;
    u16* wih0_bf = (u16*)(ws + off);                  off += (size_t)G4 * IN0 * 2;
    u16* whh0_bf = (u16*)(ws + off);                  off += (size_t)G4 * HID * 2;
    u16* wih1_bf = (u16*)(ws + off);                  off += (size_t)G4 * HID * 2;
    u16* whh1_bf = (u16*)(ws + off);                  off += (size_t)G4 * HID * 2;
    u16* fcw_bf  = (u16*)(ws + off);                  off += (size_t)OUTF * HID * 2;
    u16* y0      = (u16*)(ws + off);                  off += (size_t)T_SEQ * BATCH * HID * 2;
    u16* y1      = (u16*)(ws + off);                  off += (size_t)T_SEQ * BATCH * HID * 2;

    hipMemsetAsync(ctr, 0, flag_bytes, stream);

    auto conv = [&](const float* in, u16* o, int n) {
        int n4 = n / 4;
        cvt_f32_bf16<<<(n4 + 255) / 256, 256, 0, stream>>>(in, o, n4);
    };
    conv(x,    x_bf,    T_SEQ * BATCH * IN0);
    conv(wih0, wih0_bf, G4 * IN0);
    conv(whh0, whh0_bf, G4 * HID);
    conv(wih1, wih1_bf, G4 * HID);
    conv(whh1, whh1_bf, G4 * HID);
    conv(fcw,  fcw_bf,  OUTF * HID);

    float* outFC = out;
    float* hN = out + (size_t)T_SEQ * BATCH * OUTF;     // [2,B,H]
    float* cN = hN + 2 * BATCH * HID;                   // [2,B,H]

    lstm_fused<<<2 * NWG_L, 256, 0, stream>>>(x_bf, wih0_bf, whh0_bf, b0,
                                              wih1_bf, whh1_bf, b1,
                                              y0, y1, hN, cN, ctr);
    fc_kernel<<<256, 256, 0, stream>>>(y1, fcw_bf, fcb, outFC);
}